// Round 2
// baseline (2561.654 us; speedup 1.0000x reference)
//
#include <hip/hip_runtime.h>

#define KDIM 256
#define NB 16384
#define NR 8192

typedef unsigned short ushort_t;
typedef __attribute__((ext_vector_type(8))) short short8;
typedef __attribute__((ext_vector_type(4))) float f32x4;

// ---------------------------------------------------------------- helpers ---
__device__ __forceinline__ ushort_t f2bf(float f) {          // RNE f32->bf16
    unsigned u = __float_as_uint(f);
    unsigned r = (u + 0x7fffu + ((u >> 16) & 1u)) >> 16;
    return (ushort_t)r;
}
__device__ __forceinline__ float bf2f(ushort_t s) {
    return __uint_as_float(((unsigned)s) << 16);
}
__device__ __forceinline__ void gload16(const void* g, void* l) {
    __builtin_amdgcn_global_load_lds(
        (const __attribute__((address_space(1))) void*)g,
        (__attribute__((address_space(3))) void*)l, 16, 0, 0);
}
// insert (v,idx) into sorted top-3 (v desc, idx asc on ties)
__device__ __forceinline__ void ins3(float v, int idx,
                                     float& v0, int& i0, float& v1, int& i1,
                                     float& v2, int& i2) {
    bool b2 = (v > v2) | ((v == v2) & (idx < i2));
    if (b2) {
        bool b0 = (v > v0) | ((v == v0) & (idx < i0));
        bool b1 = (v > v1) | ((v == v1) & (idx < i1));
        if (b0)      { v2 = v1; i2 = i1; v1 = v0; i1 = i0; v0 = v; i0 = idx; }
        else if (b1) { v2 = v1; i2 = i1; v1 = v;  i1 = idx; }
        else         { v2 = v;  i2 = idx; }
    }
}

// ------------------------------------------------ split: normalize + 3xbf16 -
__global__ __launch_bounds__(256) void split_kernel(
    const float* __restrict__ base, const float* __restrict__ real,
    ushort_t* __restrict__ Ah, ushort_t* __restrict__ Am, ushort_t* __restrict__ Al,
    ushort_t* __restrict__ Bh, ushort_t* __restrict__ Bm, ushort_t* __restrict__ Bl) {
    int rid  = blockIdx.x * 4 + (threadIdx.x >> 6);
    int lane = threadIdx.x & 63;
    bool isA = rid < NB;
    int  row = isA ? rid : rid - NB;
    const float* src = isA ? base + (size_t)row * KDIM : real + (size_t)row * KDIM;
    float4 v = *(const float4*)(src + lane * 4);
    float ss = v.x * v.x + v.y * v.y + v.z * v.z + v.w * v.w;
    #pragma unroll
    for (int off = 32; off > 0; off >>= 1) ss += __shfl_xor(ss, off);
    float inv = 1.0f / fmaxf(sqrtf(ss), 1e-12f);

    float n[4] = {v.x * inv, v.y * inv, v.z * inv, v.w * inv};
    ushort_t h[4], m[4], l[4];
    #pragma unroll
    for (int e = 0; e < 4; ++e) {
        h[e] = f2bf(n[e]);
        float r1 = n[e] - bf2f(h[e]);
        m[e] = f2bf(r1);
        float r2 = r1 - bf2f(m[e]);
        l[e] = f2bf(r2);
    }
    size_t o = (size_t)row * KDIM + lane * 4;
    ushort_t* dh = isA ? Ah : Bh;
    ushort_t* dm = isA ? Am : Bm;
    ushort_t* dl = isA ? Al : Bl;
    *(ushort4*)(dh + o) = make_ushort4(h[0], h[1], h[2], h[3]);
    *(ushort4*)(dm + o) = make_ushort4(m[0], m[1], m[2], m[3]);
    *(ushort4*)(dl + o) = make_ushort4(l[0], l[1], l[2], l[3]);
}

// ------------------------------- fused 6-product bf16 MFMA GEMM + top-3 -----
// block 256 thr = 4 waves (2x2), tile 128x128, BK=64, K' = 6 products x 256.
__global__ __launch_bounds__(256) void mfma_topk_kernel(
    const ushort_t* __restrict__ Ah, const ushort_t* __restrict__ Am,
    const ushort_t* __restrict__ Al, const ushort_t* __restrict__ Bh,
    const ushort_t* __restrict__ Bm, const ushort_t* __restrict__ Bl,
    float* __restrict__ Pv, int* __restrict__ Pi) {
    __shared__ ushort_t sA[128 * 64];
    __shared__ ushort_t sB[128 * 64];

    const int tid  = threadIdx.x;
    const int lane = tid & 63;
    const int w    = tid >> 6;
    const int wr   = w >> 1, wc = w & 1;
    const int m0   = blockIdx.y * 128;
    const int n0   = blockIdx.x * 128;
    const int c    = lane & 15;       // frag col/row-in-16
    const int g    = lane >> 4;       // frag k-group
    const int lr8  = lane >> 3;       // staging: row within 8-row chunk
    const int ud   = lane & 7;        // staging: dest 16B slot within row

    f32x4 acc[4][4];
    #pragma unroll
    for (int i = 0; i < 4; ++i)
        #pragma unroll
        for (int j = 0; j < 4; ++j) acc[i][j] = (f32x4){0.f, 0.f, 0.f, 0.f};

    const ushort_t* const Ap[3] = {Ah, Am, Al};
    const ushort_t* const Bp[3] = {Bh, Bm, Bl};
    constexpr int PA[6] = {0, 0, 1, 0, 1, 2};
    constexpr int PB[6] = {0, 1, 0, 2, 1, 0};

    #pragma unroll
    for (int p = 0; p < 6; ++p) {
        const ushort_t* __restrict__ As = Ap[PA[p]];
        const ushort_t* __restrict__ Bs = Bp[PB[p]];
        #pragma unroll 1
        for (int kc = 0; kc < KDIM; kc += 64) {
            __syncthreads();   // LDS free (prev compute done)
            #pragma unroll
            for (int q = 0; q < 4; ++q) {
                int R   = (w * 4 + q) * 8;         // 8-row chunk base
                int row = R + lr8;
                int us  = ud ^ (row & 7);          // pre-swizzled source slot
                gload16(As + (size_t)(m0 + row) * KDIM + kc + us * 8,
                        (char*)sA + R * 128);
                gload16(Bs + (size_t)(n0 + row) * KDIM + kc + us * 8,
                        (char*)sB + R * 128);
            }
            __syncthreads();   // staging complete
            #pragma unroll
            for (int kk = 0; kk < 2; ++kk) {
                short8 a[4], b[4];
                int u = kk * 4 + g;
                #pragma unroll
                for (int i = 0; i < 4; ++i) {
                    int ra = wr * 64 + i * 16 + c;
                    a[i] = *(const short8*)((const char*)sA + ra * 128 +
                                            ((u ^ (ra & 7)) << 4));
                    int rb = wc * 64 + i * 16 + c;
                    b[i] = *(const short8*)((const char*)sB + rb * 128 +
                                            ((u ^ (rb & 7)) << 4));
                }
                #pragma unroll
                for (int i = 0; i < 4; ++i)
                    #pragma unroll
                    for (int j = 0; j < 4; ++j)
                        acc[i][j] = __builtin_amdgcn_mfma_f32_16x16x32_bf16(
                            a[i], b[j], acc[i][j], 0, 0, 0);
            }
        }
    }

    // ---- per-row top-3 over this block's 128 cols ----
    __syncthreads();                       // done reading tiles; reuse LDS
    float* mv = (float*)sA;                // [128][2][3]
    int*   mi = (int*)sB;
    #pragma unroll
    for (int i = 0; i < 4; ++i) {
        #pragma unroll
        for (int r = 0; r < 4; ++r) {
            float v0 = -3.0e38f, v1 = -3.0e38f, v2 = -3.0e38f;
            int   i0 = 0x7fffffff, i1 = 0x7fffffff, i2 = 0x7fffffff;
            #pragma unroll
            for (int j = 0; j < 4; ++j)
                ins3(acc[i][j][r], n0 + wc * 64 + j * 16 + c,
                     v0, i0, v1, i1, v2, i2);
            #pragma unroll
            for (int mask = 1; mask <= 8; mask <<= 1) {
                float ov0 = __shfl_xor(v0, mask), ov1 = __shfl_xor(v1, mask),
                      ov2 = __shfl_xor(v2, mask);
                int   oi0 = __shfl_xor(i0, mask), oi1 = __shfl_xor(i1, mask),
                      oi2 = __shfl_xor(i2, mask);
                ins3(ov0, oi0, v0, i0, v1, i1, v2, i2);
                ins3(ov1, oi1, v0, i0, v1, i1, v2, i2);
                ins3(ov2, oi2, v0, i0, v1, i1, v2, i2);
            }
            if (c == 0) {
                int row = wr * 64 + i * 16 + g * 4 + r;
                mv[(row * 2 + wc) * 3 + 0] = v0; mi[(row * 2 + wc) * 3 + 0] = i0;
                mv[(row * 2 + wc) * 3 + 1] = v1; mi[(row * 2 + wc) * 3 + 1] = i1;
                mv[(row * 2 + wc) * 3 + 2] = v2; mi[(row * 2 + wc) * 3 + 2] = i2;
            }
        }
    }
    __syncthreads();
    if (tid < 128) {
        float v0 = -3.0e38f, v1 = -3.0e38f, v2 = -3.0e38f;
        int   i0 = 0x7fffffff, i1 = 0x7fffffff, i2 = 0x7fffffff;
        #pragma unroll
        for (int e = 0; e < 6; ++e)
            ins3(mv[tid * 6 + e], mi[tid * 6 + e], v0, i0, v1, i1, v2, i2);
        size_t o = (size_t)(m0 + tid) * (64 * 3) + blockIdx.x * 3;
        Pv[o + 0] = v0; Pi[o + 0] = i0;
        Pv[o + 1] = v1; Pi[o + 1] = i1;
        Pv[o + 2] = v2; Pi[o + 2] = i2;
    }
}

// ---------------------------------------- stage-2: merge 64 chunks per row --
__global__ __launch_bounds__(256) void merge_kernel(
    const float* __restrict__ Pv, const int* __restrict__ Pi,
    int* __restrict__ out) {
    int row  = blockIdx.x * 4 + (threadIdx.x >> 6);
    int lane = threadIdx.x & 63;
    const float* pv = Pv + (size_t)row * 192;
    const int*   pi = Pi + (size_t)row * 192;
    float v0 = -3.0e38f, v1 = -3.0e38f, v2 = -3.0e38f;
    int   i0 = 0x7fffffff, i1 = 0x7fffffff, i2 = 0x7fffffff;
    #pragma unroll
    for (int s = 0; s < 3; ++s)
        ins3(pv[lane * 3 + s], pi[lane * 3 + s], v0, i0, v1, i1, v2, i2);
    #pragma unroll
    for (int mask = 1; mask <= 32; mask <<= 1) {
        float ov0 = __shfl_xor(v0, mask), ov1 = __shfl_xor(v1, mask),
              ov2 = __shfl_xor(v2, mask);
        int   oi0 = __shfl_xor(i0, mask), oi1 = __shfl_xor(i1, mask),
              oi2 = __shfl_xor(i2, mask);
        ins3(ov0, oi0, v0, i0, v1, i1, v2, i2);
        ins3(ov1, oi1, v0, i0, v1, i1, v2, i2);
        ins3(ov2, oi2, v0, i0, v1, i1, v2, i2);
    }
    if (lane == 0) {
        out[row * 3 + 0] = i0;
        out[row * 3 + 1] = i1;
        out[row * 3 + 2] = i2;
    }
}

// ======================= fallback (round-1 f32 path) ========================
__global__ __launch_bounds__(256) void norm_kernel(const float* __restrict__ base,
                                                   const float* __restrict__ real,
                                                   float* __restrict__ inv) {
    int rid  = blockIdx.x * 4 + (threadIdx.x >> 6);
    int lane = threadIdx.x & 63;
    if (rid >= NB + NR) return;
    const float* src = (rid < NB) ? (base + (size_t)rid * KDIM)
                                  : (real + (size_t)(rid - NB) * KDIM);
    float4 v = *(const float4*)(src + lane * 4);
    float ss = v.x * v.x + v.y * v.y + v.z * v.z + v.w * v.w;
    #pragma unroll
    for (int off = 32; off > 0; off >>= 1) ss += __shfl_xor(ss, off);
    if (lane == 0) inv[rid] = 1.0f / fmaxf(sqrtf(ss), 1e-12f);
}

#define DOT(i, j, av, bv)                                                      \
    acc[i][j] = fmaf(av.x, bv.x, acc[i][j]);                                   \
    acc[i][j] = fmaf(av.y, bv.y, acc[i][j]);                                   \
    acc[i][j] = fmaf(av.z, bv.z, acc[i][j]);                                   \
    acc[i][j] = fmaf(av.w, bv.w, acc[i][j]);

__global__ __launch_bounds__(256) void simtopk_kernel(
    const float* __restrict__ A, const float* __restrict__ B,
    const float* __restrict__ invA, const float* __restrict__ invB,
    int* __restrict__ out) {
    __shared__ float sA[64 * 68];
    __shared__ float sB[64 * 68];
    const int tid = threadIdx.x;
    const int tx  = tid & 15;
    const int ty4 = (tid >> 4) << 2;
    const int m0  = blockIdx.x * 64;
    float t3v[4][3];
    int   t3i[4][3];
    #pragma unroll
    for (int i = 0; i < 4; ++i)
        #pragma unroll
        for (int s = 0; s < 3; ++s) { t3v[i][s] = -3.0e38f; t3i[i][s] = 0x7fffffff; }
    for (int nn0 = 0; nn0 < NR; nn0 += 64) {
        float acc[4][4] = {{0.f}};
        for (int kc = 0; kc < KDIM; kc += 64) {
            __syncthreads();
            #pragma unroll
            for (int p = 0; p < 4; ++p) {
                int f = tid + (p << 8), row = f >> 4, c4 = (f & 15) << 2;
                float4 va = *(const float4*)(A + (size_t)(m0 + row) * KDIM + kc + c4);
                float  sa = invA[m0 + row];
                va.x *= sa; va.y *= sa; va.z *= sa; va.w *= sa;
                *(float4*)&sA[row * 68 + c4] = va;
                float4 vb = *(const float4*)(B + (size_t)(nn0 + row) * KDIM + kc + c4);
                float  sb = invB[nn0 + row];
                vb.x *= sb; vb.y *= sb; vb.z *= sb; vb.w *= sb;
                *(float4*)&sB[row * 68 + c4] = vb;
            }
            __syncthreads();
            #pragma unroll
            for (int k = 0; k < 64; k += 4) {
                float4 a0 = *(const float4*)&sA[(ty4 + 0) * 68 + k];
                float4 a1 = *(const float4*)&sA[(ty4 + 1) * 68 + k];
                float4 a2 = *(const float4*)&sA[(ty4 + 2) * 68 + k];
                float4 a3 = *(const float4*)&sA[(ty4 + 3) * 68 + k];
                float4 b0 = *(const float4*)&sB[(tx +  0) * 68 + k];
                float4 b1 = *(const float4*)&sB[(tx + 16) * 68 + k];
                float4 b2 = *(const float4*)&sB[(tx + 32) * 68 + k];
                float4 b3 = *(const float4*)&sB[(tx + 48) * 68 + k];
                DOT(0,0,a0,b0) DOT(0,1,a0,b1) DOT(0,2,a0,b2) DOT(0,3,a0,b3)
                DOT(1,0,a1,b0) DOT(1,1,a1,b1) DOT(1,2,a1,b2) DOT(1,3,a1,b3)
                DOT(2,0,a2,b0) DOT(2,1,a2,b1) DOT(2,2,a2,b2) DOT(2,3,a2,b3)
                DOT(3,0,a3,b0) DOT(3,1,a3,b1) DOT(3,2,a3,b2) DOT(3,3,a3,b3)
            }
        }
        #pragma unroll
        for (int i = 0; i < 4; ++i)
            #pragma unroll
            for (int j = 0; j < 4; ++j)
                ins3(acc[i][j], nn0 + tx + 16 * j,
                     t3v[i][0], t3i[i][0], t3v[i][1], t3i[i][1], t3v[i][2], t3i[i][2]);
    }
    __syncthreads();
    float* mv = sA;
    int*   mi = (int*)sB;
    #pragma unroll
    for (int i = 0; i < 4; ++i)
        #pragma unroll
        for (int s = 0; s < 3; ++s) {
            mv[(ty4 + i) * 48 + tx * 3 + s] = t3v[i][s];
            mi[(ty4 + i) * 48 + tx * 3 + s] = t3i[i][s];
        }
    __syncthreads();
    if (tid < 64) {
        float v0 = -3.0e38f, v1 = -3.0e38f, v2 = -3.0e38f;
        int   i0 = 0x7fffffff, i1 = 0x7fffffff, i2 = 0x7fffffff;
        for (int e = 0; e < 48; ++e)
            ins3(mv[tid * 48 + e], mi[tid * 48 + e], v0, i0, v1, i1, v2, i2);
        out[(m0 + tid) * 3 + 0] = i0;
        out[(m0 + tid) * 3 + 1] = i1;
        out[(m0 + tid) * 3 + 2] = i2;
    }
}

// ============================================================== launcher ====
extern "C" void kernel_launch(void* const* d_in, const int* in_sizes, int n_in,
                              void* d_out, int out_size, void* d_ws, size_t ws_size,
                              hipStream_t stream) {
    const float* base = (const float*)d_in[0];
    const float* real = (const float*)d_in[1];
    int* out = (int*)d_out;

    const size_t szA = (size_t)NB * KDIM * 2;   // one bf16 A part
    const size_t szB = (size_t)NR * KDIM * 2;   // one bf16 B part
    const size_t szP = (size_t)NB * 64 * 3 * 4; // partial v (or i)
    const size_t need = 3 * szA + 3 * szB + 2 * szP;

    if (ws_size >= need) {
        char* p = (char*)d_ws;
        ushort_t* Ah = (ushort_t*)(p);
        ushort_t* Am = (ushort_t*)(p + szA);
        ushort_t* Al = (ushort_t*)(p + 2 * szA);
        ushort_t* Bh = (ushort_t*)(p + 3 * szA);
        ushort_t* Bm = (ushort_t*)(p + 3 * szA + szB);
        ushort_t* Bl = (ushort_t*)(p + 3 * szA + 2 * szB);
        float*    Pv = (float*)  (p + 3 * szA + 3 * szB);
        int*      Pi = (int*)    (p + 3 * szA + 3 * szB + szP);

        hipLaunchKernelGGL(split_kernel, dim3((NB + NR) / 4), dim3(256), 0, stream,
                           base, real, Ah, Am, Al, Bh, Bm, Bl);
        hipLaunchKernelGGL(mfma_topk_kernel, dim3(NR / 128, NB / 128), dim3(256), 0,
                           stream, Ah, Am, Al, Bh, Bm, Bl, Pv, Pi);
        hipLaunchKernelGGL(merge_kernel, dim3(NB / 4), dim3(256), 0, stream,
                           Pv, Pi, out);
    } else {
        float* inv = (float*)d_ws;
        hipLaunchKernelGGL(norm_kernel, dim3((NB + NR) / 4), dim3(256), 0, stream,
                           base, real, inv);
        hipLaunchKernelGGL(simtopk_kernel, dim3(NB / 64), dim3(256), 0, stream,
                           base, real, inv, inv + NB, out);
    }
}

// Round 3
// 891.128 us; speedup vs baseline: 2.8746x; 2.8746x over previous
//
#include <hip/hip_runtime.h>

#define KDIM 256
#define NB 16384
#define NR 8192

typedef unsigned short ushort_t;
typedef __attribute__((ext_vector_type(8))) short short8;
typedef __attribute__((ext_vector_type(4))) float f32x4;

// ---------------------------------------------------------------- helpers ---
__device__ __forceinline__ ushort_t f2bf(float f) {          // RNE f32->bf16
    unsigned u = __float_as_uint(f);
    unsigned r = (u + 0x7fffu + ((u >> 16) & 1u)) >> 16;
    return (ushort_t)r;
}
__device__ __forceinline__ float bf2f(ushort_t s) {
    return __uint_as_float(((unsigned)s) << 16);
}
__device__ __forceinline__ void gload16(const void* g, void* l) {
    __builtin_amdgcn_global_load_lds(
        (const __attribute__((address_space(1))) void*)g,
        (__attribute__((address_space(3))) void*)l, 16, 0, 0);
}
// branchless insert of (v,idx) into sorted top-3 (v desc, idx asc on ties)
__device__ __forceinline__ void ins3(float v, int idx,
                                     float& v0, int& i0, float& v1, int& i1,
                                     float& v2, int& i2) {
    bool b0 = (v > v0) | ((v == v0) & (idx < i0));
    bool b1 = (v > v1) | ((v == v1) & (idx < i1));
    bool b2 = (v > v2) | ((v == v2) & (idx < i2));
    float nv2 = b1 ? v1 : (b2 ? v : v2);
    int   ni2 = b1 ? i1 : (b2 ? idx : i2);
    float nv1 = b0 ? v0 : (b1 ? v : v1);
    int   ni1 = b0 ? i0 : (b1 ? idx : i1);
    float nv0 = b0 ? v : v0;
    int   ni0 = b0 ? idx : i0;
    v0 = nv0; i0 = ni0; v1 = nv1; i1 = ni1; v2 = nv2; i2 = ni2;
}

// ------------------------------------------------ split: normalize + 3xbf16 -
__global__ __launch_bounds__(256) void split_kernel(
    const float* __restrict__ base, const float* __restrict__ real,
    ushort_t* __restrict__ Ah, ushort_t* __restrict__ Am, ushort_t* __restrict__ Al,
    ushort_t* __restrict__ Bh, ushort_t* __restrict__ Bm, ushort_t* __restrict__ Bl) {
    int rid  = blockIdx.x * 4 + (threadIdx.x >> 6);
    int lane = threadIdx.x & 63;
    bool isA = rid < NB;
    int  row = isA ? rid : rid - NB;
    const float* src = isA ? base + (size_t)row * KDIM : real + (size_t)row * KDIM;
    float4 v = *(const float4*)(src + lane * 4);
    float ss = v.x * v.x + v.y * v.y + v.z * v.z + v.w * v.w;
    #pragma unroll
    for (int off = 32; off > 0; off >>= 1) ss += __shfl_xor(ss, off);
    float inv = 1.0f / fmaxf(sqrtf(ss), 1e-12f);

    float n[4] = {v.x * inv, v.y * inv, v.z * inv, v.w * inv};
    ushort_t h[4], m[4], l[4];
    #pragma unroll
    for (int e = 0; e < 4; ++e) {
        h[e] = f2bf(n[e]);
        float r1 = n[e] - bf2f(h[e]);
        m[e] = f2bf(r1);
        float r2 = r1 - bf2f(m[e]);
        l[e] = f2bf(r2);
    }
    size_t o = (size_t)row * KDIM + lane * 4;
    ushort_t* dh = isA ? Ah : Bh;
    ushort_t* dm = isA ? Am : Bm;
    ushort_t* dl = isA ? Al : Bl;
    *(ushort4*)(dh + o) = make_ushort4(h[0], h[1], h[2], h[3]);
    *(ushort4*)(dm + o) = make_ushort4(m[0], m[1], m[2], m[3]);
    *(ushort4*)(dl + o) = make_ushort4(l[0], l[1], l[2], l[3]);
}

// ------------------------------- fused 6-product bf16 MFMA GEMM + top-3 -----
// block 256 thr = 4 waves (2x2), tile 128x128, BK=64, K' = 6 products x 256.
// Linear LDS layout + linear global_load_lds source (m97-faithful).
__global__ __launch_bounds__(256) void mfma_topk_kernel(
    const ushort_t* __restrict__ Ah, const ushort_t* __restrict__ Am,
    const ushort_t* __restrict__ Al, const ushort_t* __restrict__ Bh,
    const ushort_t* __restrict__ Bm, const ushort_t* __restrict__ Bl,
    float* __restrict__ Pv, int* __restrict__ Pi) {
    __shared__ ushort_t sA[128 * 64];
    __shared__ ushort_t sB[128 * 64];

    const int tid  = threadIdx.x;
    const int lane = tid & 63;
    const int w    = tid >> 6;
    const int wr   = w >> 1, wc = w & 1;
    const int c    = lane & 15;       // frag col/row-in-16
    const int kg   = lane >> 4;       // frag k-group (0..3)
    const int lr8  = lane >> 3;       // staging: row within 8-row chunk
    const int ud   = lane & 7;        // staging: 16B slot within row (linear)

    // ---- bijective XCD supertile remap: 8192 blocks = 8 XCD x 16 st x 8x8 --
    int lin = blockIdx.y * 64 + blockIdx.x;     // gridDim = (64, 128)
    int xcd = lin & 7;
    int pos = lin >> 3;                          // 0..1023
    int gg  = xcd * 1024 + pos;                  // chunked per-XCD range
    int st  = gg >> 6, in8 = gg & 63;            // supertile id, pos within
    int my  = ((st >> 3) << 3) + (in8 >> 3);     // 0..127 row tile
    int nx  = ((st & 7) << 3) + (in8 & 7);       // 0..63  col tile
    const int m0 = my * 128;
    const int n0 = nx * 128;

    f32x4 acc[4][4];
    #pragma unroll
    for (int i = 0; i < 4; ++i)
        #pragma unroll
        for (int j = 0; j < 4; ++j) acc[i][j] = (f32x4){0.f, 0.f, 0.f, 0.f};

    const ushort_t* const Ap[3] = {Ah, Am, Al};
    const ushort_t* const Bp[3] = {Bh, Bm, Bl};
    constexpr int PA[6] = {0, 0, 1, 0, 1, 2};
    constexpr int PB[6] = {0, 1, 0, 2, 1, 0};

    #pragma unroll
    for (int p = 0; p < 6; ++p) {
        const ushort_t* __restrict__ As = Ap[PA[p]];
        const ushort_t* __restrict__ Bs = Bp[PB[p]];
        #pragma unroll 1
        for (int kc = 0; kc < KDIM; kc += 64) {
            __syncthreads();   // LDS free (prev compute done)
            #pragma unroll
            for (int q = 0; q < 4; ++q) {
                int R = (w * 4 + q) * 8;           // 8-row chunk base
                gload16(As + (size_t)(m0 + R + lr8) * KDIM + kc + ud * 8,
                        (char*)sA + R * 128);
                gload16(Bs + (size_t)(n0 + R + lr8) * KDIM + kc + ud * 8,
                        (char*)sB + R * 128);
            }
            __syncthreads();   // staging complete
            #pragma unroll
            for (int kk = 0; kk < 2; ++kk) {
                short8 a[4], b[4];
                int u = kk * 4 + kg;
                #pragma unroll
                for (int i = 0; i < 4; ++i) {
                    int ra = wr * 64 + i * 16 + c;
                    a[i] = *(const short8*)(sA + ra * 64 + u * 8);
                    int rb = wc * 64 + i * 16 + c;
                    b[i] = *(const short8*)(sB + rb * 64 + u * 8);
                }
                #pragma unroll
                for (int i = 0; i < 4; ++i)
                    #pragma unroll
                    for (int j = 0; j < 4; ++j)
                        acc[i][j] = __builtin_amdgcn_mfma_f32_16x16x32_bf16(
                            a[i], b[j], acc[i][j], 0, 0, 0);
            }
        }
    }

    // ---- per-row top-3 over this block's 128 cols ----
    __syncthreads();                       // done reading tiles; reuse LDS
    float* mv = (float*)sA;                // [128][2][3]
    int*   mi = (int*)sB;
    #pragma unroll
    for (int i = 0; i < 4; ++i) {
        #pragma unroll
        for (int r = 0; r < 4; ++r) {
            float v0 = -3.0e38f, v1 = -3.0e38f, v2 = -3.0e38f;
            int   i0 = 0x7fffffff, i1 = 0x7fffffff, i2 = 0x7fffffff;
            #pragma unroll
            for (int j = 0; j < 4; ++j)
                ins3(acc[i][j][r], n0 + wc * 64 + j * 16 + c,
                     v0, i0, v1, i1, v2, i2);
            #pragma unroll
            for (int mask = 1; mask <= 8; mask <<= 1) {
                float ov0 = __shfl_xor(v0, mask), ov1 = __shfl_xor(v1, mask),
                      ov2 = __shfl_xor(v2, mask);
                int   oi0 = __shfl_xor(i0, mask), oi1 = __shfl_xor(i1, mask),
                      oi2 = __shfl_xor(i2, mask);
                ins3(ov0, oi0, v0, i0, v1, i1, v2, i2);
                ins3(ov1, oi1, v0, i0, v1, i1, v2, i2);
                ins3(ov2, oi2, v0, i0, v1, i1, v2, i2);
            }
            if (c == 0) {
                int row = wr * 64 + i * 16 + kg * 4 + r;
                mv[(row * 2 + wc) * 3 + 0] = v0; mi[(row * 2 + wc) * 3 + 0] = i0;
                mv[(row * 2 + wc) * 3 + 1] = v1; mi[(row * 2 + wc) * 3 + 1] = i1;
                mv[(row * 2 + wc) * 3 + 2] = v2; mi[(row * 2 + wc) * 3 + 2] = i2;
            }
        }
    }
    __syncthreads();
    if (tid < 128) {
        float v0 = -3.0e38f, v1 = -3.0e38f, v2 = -3.0e38f;
        int   i0 = 0x7fffffff, i1 = 0x7fffffff, i2 = 0x7fffffff;
        #pragma unroll
        for (int e = 0; e < 6; ++e)
            ins3(mv[tid * 6 + e], mi[tid * 6 + e], v0, i0, v1, i1, v2, i2);
        size_t o = (size_t)(m0 + tid) * (64 * 3) + nx * 3;
        Pv[o + 0] = v0; Pi[o + 0] = i0;
        Pv[o + 1] = v1; Pi[o + 1] = i1;
        Pv[o + 2] = v2; Pi[o + 2] = i2;
    }
}

// ---------------------------------------- stage-2: merge 64 chunks per row --
__global__ __launch_bounds__(256) void merge_kernel(
    const float* __restrict__ Pv, const int* __restrict__ Pi,
    int* __restrict__ out) {
    int row  = blockIdx.x * 4 + (threadIdx.x >> 6);
    int lane = threadIdx.x & 63;
    const float* pv = Pv + (size_t)row * 192;
    const int*   pi = Pi + (size_t)row * 192;
    float v0 = -3.0e38f, v1 = -3.0e38f, v2 = -3.0e38f;
    int   i0 = 0x7fffffff, i1 = 0x7fffffff, i2 = 0x7fffffff;
    #pragma unroll
    for (int s = 0; s < 3; ++s)
        ins3(pv[lane * 3 + s], pi[lane * 3 + s], v0, i0, v1, i1, v2, i2);
    #pragma unroll
    for (int mask = 1; mask <= 32; mask <<= 1) {
        float ov0 = __shfl_xor(v0, mask), ov1 = __shfl_xor(v1, mask),
              ov2 = __shfl_xor(v2, mask);
        int   oi0 = __shfl_xor(i0, mask), oi1 = __shfl_xor(i1, mask),
              oi2 = __shfl_xor(i2, mask);
        ins3(ov0, oi0, v0, i0, v1, i1, v2, i2);
        ins3(ov1, oi1, v0, i0, v1, i1, v2, i2);
        ins3(ov2, oi2, v0, i0, v1, i1, v2, i2);
    }
    if (lane == 0) {
        out[row * 3 + 0] = i0;
        out[row * 3 + 1] = i1;
        out[row * 3 + 2] = i2;
    }
}

// ======================= fallback (round-1 f32 path) ========================
__global__ __launch_bounds__(256) void norm_kernel(const float* __restrict__ base,
                                                   const float* __restrict__ real,
                                                   float* __restrict__ inv) {
    int rid  = blockIdx.x * 4 + (threadIdx.x >> 6);
    int lane = threadIdx.x & 63;
    if (rid >= NB + NR) return;
    const float* src = (rid < NB) ? (base + (size_t)rid * KDIM)
                                  : (real + (size_t)(rid - NB) * KDIM);
    float4 v = *(const float4*)(src + lane * 4);
    float ss = v.x * v.x + v.y * v.y + v.z * v.z + v.w * v.w;
    #pragma unroll
    for (int off = 32; off > 0; off >>= 1) ss += __shfl_xor(ss, off);
    if (lane == 0) inv[rid] = 1.0f / fmaxf(sqrtf(ss), 1e-12f);
}

#define DOT(i, j, av, bv)                                                      \
    acc[i][j] = fmaf(av.x, bv.x, acc[i][j]);                                   \
    acc[i][j] = fmaf(av.y, bv.y, acc[i][j]);                                   \
    acc[i][j] = fmaf(av.z, bv.z, acc[i][j]);                                   \
    acc[i][j] = fmaf(av.w, bv.w, acc[i][j]);

__global__ __launch_bounds__(256) void simtopk_kernel(
    const float* __restrict__ A, const float* __restrict__ B,
    const float* __restrict__ invA, const float* __restrict__ invB,
    int* __restrict__ out) {
    __shared__ float sA[64 * 68];
    __shared__ float sB[64 * 68];
    const int tid = threadIdx.x;
    const int tx  = tid & 15;
    const int ty4 = (tid >> 4) << 2;
    const int m0  = blockIdx.x * 64;
    float t3v[4][3];
    int   t3i[4][3];
    #pragma unroll
    for (int i = 0; i < 4; ++i)
        #pragma unroll
        for (int s = 0; s < 3; ++s) { t3v[i][s] = -3.0e38f; t3i[i][s] = 0x7fffffff; }
    for (int nn0 = 0; nn0 < NR; nn0 += 64) {
        float acc[4][4] = {{0.f}};
        for (int kc = 0; kc < KDIM; kc += 64) {
            __syncthreads();
            #pragma unroll
            for (int p = 0; p < 4; ++p) {
                int f = tid + (p << 8), row = f >> 4, c4 = (f & 15) << 2;
                float4 va = *(const float4*)(A + (size_t)(m0 + row) * KDIM + kc + c4);
                float  sa = invA[m0 + row];
                va.x *= sa; va.y *= sa; va.z *= sa; va.w *= sa;
                *(float4*)&sA[row * 68 + c4] = va;
                float4 vb = *(const float4*)(B + (size_t)(nn0 + row) * KDIM + kc + c4);
                float  sb = invB[nn0 + row];
                vb.x *= sb; vb.y *= sb; vb.z *= sb; vb.w *= sb;
                *(float4*)&sB[row * 68 + c4] = vb;
            }
            __syncthreads();
            #pragma unroll
            for (int k = 0; k < 64; k += 4) {
                float4 a0 = *(const float4*)&sA[(ty4 + 0) * 68 + k];
                float4 a1 = *(const float4*)&sA[(ty4 + 1) * 68 + k];
                float4 a2 = *(const float4*)&sA[(ty4 + 2) * 68 + k];
                float4 a3 = *(const float4*)&sA[(ty4 + 3) * 68 + k];
                float4 b0 = *(const float4*)&sB[(tx +  0) * 68 + k];
                float4 b1 = *(const float4*)&sB[(tx + 16) * 68 + k];
                float4 b2 = *(const float4*)&sB[(tx + 32) * 68 + k];
                float4 b3 = *(const float4*)&sB[(tx + 48) * 68 + k];
                DOT(0,0,a0,b0) DOT(0,1,a0,b1) DOT(0,2,a0,b2) DOT(0,3,a0,b3)
                DOT(1,0,a1,b0) DOT(1,1,a1,b1) DOT(1,2,a1,b2) DOT(1,3,a1,b3)
                DOT(2,0,a2,b0) DOT(2,1,a2,b1) DOT(2,2,a2,b2) DOT(2,3,a2,b3)
                DOT(3,0,a3,b0) DOT(3,1,a3,b1) DOT(3,2,a3,b2) DOT(3,3,a3,b3)
            }
        }
        #pragma unroll
        for (int i = 0; i < 4; ++i)
            #pragma unroll
            for (int j = 0; j < 4; ++j)
                ins3(acc[i][j], nn0 + tx + 16 * j,
                     t3v[i][0], t3i[i][0], t3v[i][1], t3i[i][1], t3v[i][2], t3i[i][2]);
    }
    __syncthreads();
    float* mv = sA;
    int*   mi = (int*)sB;
    #pragma unroll
    for (int i = 0; i < 4; ++i)
        #pragma unroll
        for (int s = 0; s < 3; ++s) {
            mv[(ty4 + i) * 48 + tx * 3 + s] = t3v[i][s];
            mi[(ty4 + i) * 48 + tx * 3 + s] = t3i[i][s];
        }
    __syncthreads();
    if (tid < 64) {
        float v0 = -3.0e38f, v1 = -3.0e38f, v2 = -3.0e38f;
        int   i0 = 0x7fffffff, i1 = 0x7fffffff, i2 = 0x7fffffff;
        for (int e = 0; e < 48; ++e)
            ins3(mv[tid * 48 + e], mi[tid * 48 + e], v0, i0, v1, i1, v2, i2);
        out[(m0 + tid) * 3 + 0] = i0;
        out[(m0 + tid) * 3 + 1] = i1;
        out[(m0 + tid) * 3 + 2] = i2;
    }
}

// ============================================================== launcher ====
extern "C" void kernel_launch(void* const* d_in, const int* in_sizes, int n_in,
                              void* d_out, int out_size, void* d_ws, size_t ws_size,
                              hipStream_t stream) {
    const float* base = (const float*)d_in[0];
    const float* real = (const float*)d_in[1];
    int* out = (int*)d_out;

    const size_t szA = (size_t)NB * KDIM * 2;   // one bf16 A part
    const size_t szB = (size_t)NR * KDIM * 2;   // one bf16 B part
    const size_t szP = (size_t)NB * 64 * 3 * 4; // partial v (or i)
    const size_t need = 3 * szA + 3 * szB + 2 * szP;

    if (ws_size >= need) {
        char* p = (char*)d_ws;
        ushort_t* Ah = (ushort_t*)(p);
        ushort_t* Am = (ushort_t*)(p + szA);
        ushort_t* Al = (ushort_t*)(p + 2 * szA);
        ushort_t* Bh = (ushort_t*)(p + 3 * szA);
        ushort_t* Bm = (ushort_t*)(p + 3 * szA + szB);
        ushort_t* Bl = (ushort_t*)(p + 3 * szA + 2 * szB);
        float*    Pv = (float*)  (p + 3 * szA + 3 * szB);
        int*      Pi = (int*)    (p + 3 * szA + 3 * szB + szP);

        hipLaunchKernelGGL(split_kernel, dim3((NB + NR) / 4), dim3(256), 0, stream,
                           base, real, Ah, Am, Al, Bh, Bm, Bl);
        hipLaunchKernelGGL(mfma_topk_kernel, dim3(NR / 128, NB / 128), dim3(256), 0,
                           stream, Ah, Am, Al, Bh, Bm, Bl, Pv, Pi);
        hipLaunchKernelGGL(merge_kernel, dim3(NB / 4), dim3(256), 0, stream,
                           Pv, Pi, out);
    } else {
        float* inv = (float*)d_ws;
        hipLaunchKernelGGL(norm_kernel, dim3((NB + NR) / 4), dim3(256), 0, stream,
                           base, real, inv);
        hipLaunchKernelGGL(simtopk_kernel, dim3(NB / 64), dim3(256), 0, stream,
                           base, real, inv, inv + NB, out);
    }
}